// Round 13
// baseline (1046.173 us; speedup 1.0000x reference)
//
#include <hip/hip_runtime.h>
#include <hip/hip_bf16.h>

// Problem constants
#define NB    65536      // batch rows
#define KDIM  1024       // reduction dim for all projections
#define NDIM  1024       // output dim per projection

// 128x128 GEMM geometry, BK=32, double-buffered (32 KB LDS -> 4 blocks/CU)
#define BM 128
#define BN 128
#define BK 32
#define NT (KDIM / BK)   // 32 K-tiles

typedef float f32x4  __attribute__((ext_vector_type(4)));
typedef short short8 __attribute__((ext_vector_type(8)));
typedef unsigned short ushort8v __attribute__((ext_vector_type(8)));

static __device__ __forceinline__ unsigned short f2bf(float f) {
    union { float f; unsigned u; } v; v.f = f;
    unsigned r = v.u + 0x7FFFu + ((v.u >> 16) & 1u);
    return (unsigned short)(r >> 16);
}
static __device__ __forceinline__ float bf2f(unsigned short h) {
    union { unsigned u; float f; } v; v.u = ((unsigned)h) << 16;
    return v.f;
}

// async global->LDS, 16B per lane. LDS dest = wave-uniform base + lane*16.
static __device__ __forceinline__ void gload16(const unsigned short* g, unsigned short* l) {
    __builtin_amdgcn_global_load_lds(
        (const __attribute__((address_space(1))) unsigned int*)g,
        (__attribute__((address_space(3))) unsigned int*)l, 16, 0, 0);
}

// ---------------------------------------------------------------------------
// PACKED LAYOUT (GEMM-consumption order; r10: cold 64B-scatter caps at
// 1.98 TB/s; r11: packing -> 900 TF streaming):
//   1KB chunk index = ((r>>8)*32 + t)*16 + ((r>>4)&15)
//   inner (shorts)  = kc*128 + (r&15)*8 + pos,  col c = t*32 + kc*8 + pos
// One chunk, read at lane*16B, IS one complete 16-row x 32-k MFMA fragment
// set (row = lane&15, k-off = (lane>>4)*8) -- zero-conflict, zero-rearrange.
// ---------------------------------------------------------------------------

// fp32 row-major [nrows][1024] -> packed bf16. One 16-row f-stripe per block.
__global__ __launch_bounds__(256) void pack_f32_k(
    const float* __restrict__ src, unsigned short* __restrict__ dst)
{
    const int tid = threadIdx.x;
    const int r   = blockIdx.x * 16 + (tid >> 4);   // global row
    const int cb  = (tid & 15) * 64;                // 64 cols per thread
    const int p   = r >> 8;
    const int f   = (r >> 4) & 15;
    const int rl  = r & 15;
    const float* s = src + (size_t)r * 1024 + cb;
#pragma unroll
    for (int g = 0; g < 8; ++g) {
        float4 va = *reinterpret_cast<const float4*>(s + g * 8);
        float4 vb = *reinterpret_cast<const float4*>(s + g * 8 + 4);
        ushort8v o;
        o[0] = f2bf(va.x); o[1] = f2bf(va.y); o[2] = f2bf(va.z); o[3] = f2bf(va.w);
        o[4] = f2bf(vb.x); o[5] = f2bf(vb.y); o[6] = f2bf(vb.z); o[7] = f2bf(vb.w);
        const int c0 = cb + g * 8;
        const int t  = c0 >> 5;
        const int kc = (c0 & 31) >> 3;
        *reinterpret_cast<ushort8v*>(
            &dst[((size_t)(p * 32 + t) * 16 + f) * 512 + kc * 128 + rl * 8]) = o;
    }
}

// ---------------------------------------------------------------------------
// 128x128 GEMM, BK=32, dbuf 32 KB, 4 BLOCKS/CU CO-RESIDENT (m114 mechanism:
// one block's vmcnt/barrier drain hides under the other blocks' MFMA --
// first occupancy test in the packed regime; r11/r12 ran 1 block/CU @23%).
// 256 thr = 4 waves (2 Mw x 2 Nw), per-wave output 64x64.
// Per K-tile: { STAGE(t+1)->other slot (4 gloads/wave); 8 ds_reads;
//               16 MFMA; vmcnt(0); barrier }  (m97 2-barrier classic)
// Overwrite safety: STAGE(t+1) hits slot read in tile t-1, whose reads
// completed (lgkm-before-MFMA) before bar(t-1) < issue. vmcnt(0) at tile
// end validates slot t+1. Epilogue: LDS bounce -> full-line stores.
// ---------------------------------------------------------------------------
template<int OUT_F32, int NN>
__global__ __launch_bounds__(256, 4) void gemm128(
    const unsigned short* __restrict__ Ap, const unsigned short* __restrict__ Wp,
    const float* __restrict__ bias, void* __restrict__ Cptr)
{
    constexpr int GN = NN / BN;              // 8 or 16 col tiles
    // [slot][A|B][chunk(16 rows x 32 k)][512 shorts] = 32 KB
    __shared__ alignas(16) unsigned short lds[2][2][8][512];

    const int t    = threadIdx.x;
    const int lane = t & 63;
    const int wid  = t >> 6;                 // 0..3
    const int wm   = wid >> 1;               // 0..1  (64 rows each)
    const int wn   = wid & 1;                // 0..1  (64 cols each)

    // XCD-chunked swizzle (nwg % 8 == 0): same-panel blocks share one L2
    const int nwg  = gridDim.x;
    const int cpx  = nwg >> 3;
    const int orig = blockIdx.x;
    const int wgid = (orig & 7) * cpx + (orig >> 3);
    const int bn0  = (wgid & (GN - 1)) * BN;
    const int bm0  = (wgid / GN) * BM;

    const int pA  = bm0 >> 8;  const int f0A = (bm0 >> 4) & 15;
    const int pB  = bn0 >> 8;  const int f0B = (bn0 >> 4) & 15;

    // stage K-tile TAU (A and B, 8 chunks each) into slot SLOT: 4 gloads/wave
#define STAGE_(TAU, SLOT) do {                                                  \
        int _tc = (TAU) < NT ? (TAU) : NT - 1;                                  \
        _Pragma("unroll")                                                       \
        for (int _ab = 0; _ab < 2; ++_ab) {                                     \
            const unsigned short* _b = _ab ? Wp : Ap;                           \
            int _pp = _ab ? pB : pA;                                            \
            int _f0 = _ab ? f0B : f0A;                                          \
            _Pragma("unroll")                                                   \
            for (int _j = 0; _j < 2; ++_j) {                                    \
                int _f = wid * 2 + _j;                                          \
                gload16(_b + ((size_t)(_pp * 32 + _tc) * 16 + _f0 + _f) * 512 + lane * 8, \
                        &lds[SLOT][_ab][_f][0]);                                \
            }                                                                   \
        }                                                                       \
    } while (0)

    f32x4 acc[4][4];
#pragma unroll
    for (int mi = 0; mi < 4; ++mi)
#pragma unroll
        for (int ni = 0; ni < 4; ++ni)
            acc[mi][ni] = (f32x4){0.f, 0.f, 0.f, 0.f};

    // prologue
    STAGE_(0, 0);
    asm volatile("s_waitcnt vmcnt(0)" ::: "memory");
    __builtin_amdgcn_s_barrier();

#pragma unroll 1
    for (int tt = 0; tt < NT; ++tt) {
        const int slot = tt & 1;
        if (tt + 1 < NT) STAGE_(tt + 1, slot ^ 1);

        short8 af[4], bq[4];
#pragma unroll
        for (int mi = 0; mi < 4; ++mi)
            af[mi] = *reinterpret_cast<const short8*>(&lds[slot][0][wm * 4 + mi][lane * 8]);
#pragma unroll
        for (int ni = 0; ni < 4; ++ni)
            bq[ni] = *reinterpret_cast<const short8*>(&lds[slot][1][wn * 4 + ni][lane * 8]);
        __builtin_amdgcn_s_setprio(1);
#pragma unroll
        for (int mi = 0; mi < 4; ++mi)
#pragma unroll
            for (int ni = 0; ni < 4; ++ni)
                acc[mi][ni] = __builtin_amdgcn_mfma_f32_16x16x32_bf16(
                    af[mi], bq[ni], acc[mi][ni], 0, 0, 0);
        __builtin_amdgcn_s_setprio(0);
        asm volatile("s_waitcnt vmcnt(0)" ::: "memory");  // next tile landed
        __builtin_amdgcn_s_barrier();
    }

    // epilogue: LDS bounce -> coalesced full-line stores
    // acc fragment: D row = (lane>>4)*4 + r, col = lane&15  [m89-verified]
    const int crow = (lane >> 4) * 4;
    const int ccol = lane & 15;

    if (OUT_F32) {
        float* Cf  = (float*)Cptr;
        float* bbf = reinterpret_cast<float*>(&lds[0][0][0][0]);
        float bv[4];
#pragma unroll
        for (int ni = 0; ni < 4; ++ni)
            bv[ni] = bias[bn0 + wn * 64 + ni * 16 + ccol];
        // 4 passes x 32 rows; stride 136 floats (32*136*4 = 17.4 KB <= 32 KB)
#pragma unroll
        for (int p = 0; p < 4; ++p) {
            if (wm == (p >> 1)) {
#pragma unroll
                for (int mlo = 0; mlo < 2; ++mlo) {
                    int ml = (p & 1) * 2 + mlo;
#pragma unroll
                    for (int ni = 0; ni < 4; ++ni)
#pragma unroll
                        for (int r = 0; r < 4; ++r)
                            bbf[(mlo * 16 + crow + r) * 136 + wn * 64 + ni * 16 + ccol]
                                = acc[ml][ni][r] + bv[ni];
                }
            }
            __syncthreads();
#pragma unroll
            for (int it = 0; it < 4; ++it) {
                int lrow = it * 8 + (t >> 5);            // 0..31
                int lcol = (t & 31) * 4;                 // 0..124
                f32x4 v = *reinterpret_cast<const f32x4*>(&bbf[lrow * 136 + lcol]);
                *reinterpret_cast<f32x4*>(
                    &Cf[(size_t)(bm0 + p * 32 + lrow) * NN + bn0 + lcol]) = v;
            }
            __syncthreads();
        }
    } else {
        unsigned short* Cb = (unsigned short*)Cptr;
        unsigned short* bb = &lds[0][0][0][0];
        // 2 passes x 64 rows; stride 136 shorts (64*136*2 = 17.4 KB <= 32 KB)
#pragma unroll
        for (int p = 0; p < 2; ++p) {
            if (wm == p) {
#pragma unroll
                for (int ml = 0; ml < 4; ++ml)
#pragma unroll
                    for (int ni = 0; ni < 4; ++ni)
#pragma unroll
                        for (int r = 0; r < 4; ++r)
                            bb[(ml * 16 + crow + r) * 136 + wn * 64 + ni * 16 + ccol]
                                = f2bf(acc[ml][ni][r]);
            }
            __syncthreads();
#pragma unroll
            for (int it = 0; it < 4; ++it) {
                int lrow = it * 16 + (t >> 4);           // 0..63
                int lcol = (t & 15) * 8;                 // 0..120
                ushort8v v = *reinterpret_cast<const ushort8v*>(&bb[lrow * 136 + lcol]);
                *reinterpret_cast<ushort8v*>(
                    &Cb[(size_t)(bm0 + p * 64 + lrow) * NN + bn0 + lcol]) = v;
            }
            __syncthreads();
        }
    }
#undef STAGE_
}

// ---------------------------------------------------------------------------
// Per-row attention, 16 rows/block (16 waves), wave-per-row body.
// Reads Q (row-major) + fused KV (row stride 2048); writes feats PACKED.
// ---------------------------------------------------------------------------
__global__ __launch_bounds__(1024) void attn_k(
    const unsigned short* __restrict__ Qb, const unsigned short* __restrict__ KVb,
    unsigned short* __restrict__ Fp)
{
    __shared__ alignas(16) unsigned short KL[16][1024];   // K rows; reused as feats
    __shared__ alignas(16) unsigned short VL[16][1024];
    const int t = threadIdx.x;
    const int lane = t & 63;
    const int wid = t >> 6;                       // 0..15
    const size_t row = (size_t)blockIdx.x * 16 + wid;
    const size_t base = row * 1024;
    const size_t bkv  = row * 2048;
    const int off = lane * 16;

    ushort8v q0 = *reinterpret_cast<const ushort8v*>(&Qb[base + off]);
    ushort8v q1 = *reinterpret_cast<const ushort8v*>(&Qb[base + off + 8]);
    float qf[16];
#pragma unroll
    for (int j = 0; j < 8; ++j) { qf[j] = bf2f(q0[j]); qf[8 + j] = bf2f(q1[j]); }

    *reinterpret_cast<ushort8v*>(&KL[wid][off])     = *reinterpret_cast<const ushort8v*>(&KVb[bkv + off]);
    *reinterpret_cast<ushort8v*>(&KL[wid][off + 8]) = *reinterpret_cast<const ushort8v*>(&KVb[bkv + off + 8]);
    *reinterpret_cast<ushort8v*>(&VL[wid][off])     = *reinterpret_cast<const ushort8v*>(&KVb[bkv + 1024 + off]);
    *reinterpret_cast<ushort8v*>(&VL[wid][off + 8]) = *reinterpret_cast<const ushort8v*>(&KVb[bkv + 1024 + off + 8]);
    __syncthreads();

    const int sub = lane & 3;
    float s[16];
#pragma unroll
    for (int g = 0; g < 16; ++g) {
        const ushort8v k0 = *reinterpret_cast<const ushort8v*>(&KL[wid][g * 64 + sub * 16]);
        const ushort8v k1 = *reinterpret_cast<const ushort8v*>(&KL[wid][g * 64 + sub * 16 + 8]);
        float acc = 0.f;
#pragma unroll
        for (int j = 0; j < 8; ++j)
            acc += qf[j] * bf2f(k0[j]) + qf[8 + j] * bf2f(k1[j]);
        s[g] = acc;
    }
#pragma unroll
    for (int m = 1; m <= 2; m <<= 1)
#pragma unroll
        for (int g = 0; g < 16; ++g)
            s[g] += __shfl_xor(s[g], m, 64);

    float mx = s[0];
#pragma unroll
    for (int g = 1; g < 16; ++g) mx = fmaxf(mx, s[g]);
    float p[16], denom = 0.f;
#pragma unroll
    for (int g = 0; g < 16; ++g) {
        p[g] = __expf((s[g] - mx) * 0.125f);
        denom += p[g];
    }
    float inv = 1.f / denom;

    float f[16];
#pragma unroll
    for (int j = 0; j < 16; ++j) f[j] = 0.f;
#pragma unroll
    for (int g = 0; g < 16; ++g) {
        float pg = p[g] * inv;
        const ushort8v v0 = *reinterpret_cast<const ushort8v*>(&VL[wid][g * 64 + sub * 16]);
        const ushort8v v1 = *reinterpret_cast<const ushort8v*>(&VL[wid][g * 64 + sub * 16 + 8]);
#pragma unroll
        for (int j = 0; j < 8; ++j) {
            f[j]     += pg * bf2f(v0[j]);
            f[8 + j] += pg * bf2f(v1[j]);
        }
    }
    ushort8v o0, o1;
#pragma unroll
    for (int j = 0; j < 8; ++j) { o0[j] = f2bf(f[j]); o1[j] = f2bf(f[8 + j]); }
    // stash row into feats LDS (= KL; own-wave region, own reads long done)
    *reinterpret_cast<ushort8v*>(&KL[wid][off])     = o0;
    *reinterpret_cast<ushort8v*>(&KL[wid][off + 8]) = o1;
    __syncthreads();

    // cooperative packed write: block = f-stripe (p, f); 32KB total
    const int r0 = blockIdx.x * 16;
    const int pp = r0 >> 8;
    const int ff = (r0 >> 4) & 15;
    const int tt = t >> 5;          // tile 0..31
    const int kc = (t >> 3) & 3;    // k-chunk 0..3
    const int rp = t & 7;           // row pair 0..7
    unsigned short* db = &Fp[((size_t)(pp * 32 + tt) * 16 + ff) * 512 + kc * 128 + rp * 16];
    *reinterpret_cast<ushort8v*>(db)     = *reinterpret_cast<const ushort8v*>(&KL[rp * 2][tt * 32 + kc * 8]);
    *reinterpret_cast<ushort8v*>(db + 8) = *reinterpret_cast<const ushort8v*>(&KL[rp * 2 + 1][tt * 32 + kc * 8]);
}

// ---------------------------------------------------------------------------
extern "C" void kernel_launch(void* const* d_in, const int* in_sizes, int n_in,
                              void* d_out, int out_size, void* d_ws, size_t ws_size,
                              hipStream_t stream)
{
    (void)in_sizes; (void)n_in; (void)out_size; (void)ws_size;
    const float* latent = (const float*)d_in[0];
    const float* cond   = (const float*)d_in[1];
    const float* Wq     = (const float*)d_in[2];
    const float* Wk     = (const float*)d_in[3];
    const float* Wv     = (const float*)d_in[4];
    const float* Wout   = (const float*)d_in[5];
    const float* bout   = (const float*)d_in[6];
    float* out = (float*)d_out;

    char* ws = (char*)d_ws;
    const size_t MB = 1ull << 20;
    unsigned short* wqp  = (unsigned short*)(ws + 0 * MB);    // 2 MB packed Wq
    unsigned short* wkvp = (unsigned short*)(ws + 2 * MB);    // 4 MB packed [Wk;Wv]
    unsigned short* wop  = (unsigned short*)(ws + 6 * MB);    // 2 MB packed Wout
    unsigned short* Qb   = (unsigned short*)(ws + 8 * MB);    // 128 MB row-major Q
    unsigned short* KVb  = (unsigned short*)(ws + 136 * MB);  // 256 MB row-major fused K|V
    unsigned short* Lp   = (unsigned short*)(ws + 392 * MB);  // 128 MB packed latent; reused as packed feats
    unsigned short* Cp   = (unsigned short*)(ws + 520 * MB);  // 128 MB packed cond
    unsigned short* Fp   = Lp;                                // Lp dead after GEMM-Q

    // weight packs (tiny)
    pack_f32_k<<<NDIM / 16, 256, 0, stream>>>(Wq,   wqp);
    pack_f32_k<<<NDIM / 16, 256, 0, stream>>>(Wk,   wkvp);
    pack_f32_k<<<NDIM / 16, 256, 0, stream>>>(Wv,   wkvp + 1048576);  // panels 4..7
    pack_f32_k<<<NDIM / 16, 256, 0, stream>>>(Wout, wop);

    // activation packs (fp32 -> packed bf16)
    pack_f32_k<<<NB / 16, 256, 0, stream>>>(latent, Lp);
    pack_f32_k<<<NB / 16, 256, 0, stream>>>(cond,   Cp);

    // Q projection (N=1024) and fused K|V projection (N=2048, W stacked)
    gemm128<0, 1024><<<(NB / 128) * (1024 / 128), 256, 0, stream>>>(Lp, wqp,  nullptr, Qb);
    gemm128<0, 2048><<<(NB / 128) * (2048 / 128), 256, 0, stream>>>(Cp, wkvp, nullptr, KVb);

    // attention: row-major Q/KV in, PACKED feats out (into Fp = Lp)
    attn_k<<<NB / 16, 1024, 0, stream>>>(Qb, KVb, Fp);

    // output projection reads packed feats
    gemm128<1, 1024><<<(NB / 128) * (1024 / 128), 256, 0, stream>>>(Fp, wop, bout, out);
}